// Round 1
// baseline (808.257 us; speedup 1.0000x reference)
//
#include <hip/hip_runtime.h>

// ---------------------------------------------------------------------------
// GraphSAGE 2-layer (SAGEConv mean-aggr) on MI355X.
// Pipeline per call (ws re-poisoned every call, so CSR is rebuilt each time):
//   1. deg histogram (int atomics)
//   2. exclusive scan of deg -> CSR offsets (3-kernel scan)
//   3. scatter edges into CSR by dst (int atomics for slot cursor)
//   4. agg<128>: mean over neighbors of x -> mean1   (atomic-free, 1 wave/node)
//   5. gemm_dual: h = relu(mean1@Wl1 + x@Wr1 + bl1)
//   6. agg<256>: mean over neighbors of h -> mean2
//   7. gemm_dual: out = mean2@Wl2 + h@Wr2 + bl2
// ---------------------------------------------------------------------------

#define IN_DIM 128
#define HID_DIM 256
#define OUT_DIM 128

// -------------------- CSR build --------------------

__global__ void hist_kernel(const int* __restrict__ dst, int n_edges,
                            int* __restrict__ deg) {
    int i = blockIdx.x * blockDim.x + threadIdx.x;
    if (i < n_edges) atomicAdd(&deg[dst[i]], 1);
}

__global__ void block_sum_kernel(const int* __restrict__ deg, int n,
                                 int* __restrict__ bsums) {
    __shared__ int s[256];
    int i = blockIdx.x * 256 + threadIdx.x;
    s[threadIdx.x] = (i < n) ? deg[i] : 0;
    __syncthreads();
    for (int off = 128; off > 0; off >>= 1) {
        if (threadIdx.x < off) s[threadIdx.x] += s[threadIdx.x + off];
        __syncthreads();
    }
    if (threadIdx.x == 0) bsums[blockIdx.x] = s[0];
}

__global__ void scan_bsums_kernel(int* __restrict__ bsums, int nblk) {
    // single block, Hillis-Steele inclusive -> exclusive  (nblk <= 256)
    __shared__ int s[256];
    int t = threadIdx.x;
    int v = (t < nblk) ? bsums[t] : 0;
    s[t] = v;
    __syncthreads();
    for (int off = 1; off < 256; off <<= 1) {
        int add = (t >= off) ? s[t - off] : 0;
        __syncthreads();
        s[t] += add;
        __syncthreads();
    }
    if (t < nblk) bsums[t] = s[t] - v;
}

__global__ void finalize_kernel(const int* __restrict__ deg,
                                const int* __restrict__ bsums,
                                int n, int n_edges,
                                int* __restrict__ offs, int* __restrict__ cursor,
                                float* __restrict__ inv_deg) {
    __shared__ int s[256];
    int t = threadIdx.x;
    int i = blockIdx.x * 256 + t;
    int v = (i < n) ? deg[i] : 0;
    s[t] = v;
    __syncthreads();
    for (int off = 1; off < 256; off <<= 1) {
        int add = (t >= off) ? s[t - off] : 0;
        __syncthreads();
        s[t] += add;
        __syncthreads();
    }
    if (i < n) {
        int excl = bsums[blockIdx.x] + s[t] - v;  // exclusive prefix
        offs[i] = excl;
        cursor[i] = excl;
        inv_deg[i] = 1.0f / (float)(v > 0 ? v : 1);
    }
    if (i == 0) offs[n] = n_edges;
}

__global__ void scatter_kernel(const int* __restrict__ src,
                               const int* __restrict__ dst, int n_edges,
                               int* __restrict__ cursor, int* __restrict__ csr) {
    int i = blockIdx.x * blockDim.x + threadIdx.x;
    if (i < n_edges) {
        int p = atomicAdd(&cursor[dst[i]], 1);
        csr[p] = src[i];
    }
}

// -------------------- mean aggregation (atomic-free, 1 wave per node) -------

template <int D>
__global__ __launch_bounds__(256) void agg_kernel(
    const float* __restrict__ feat, const int* __restrict__ offs,
    const int* __restrict__ csr, const float* __restrict__ inv_deg,
    int n_nodes, float* __restrict__ mean_out) {
    int wave = threadIdx.x >> 6;
    int lane = threadIdx.x & 63;
    int node = blockIdx.x * 4 + wave;
    if (node >= n_nodes) return;
    int beg = offs[node], end = offs[node + 1];
    constexpr int R = D / 64;
    float acc[R];
#pragma unroll
    for (int j = 0; j < R; j++) acc[j] = 0.f;
    int i = beg;
    for (; i + 4 <= end; i += 4) {
        int s0 = csr[i], s1 = csr[i + 1], s2 = csr[i + 2], s3 = csr[i + 3];
        const float* r0 = feat + (size_t)s0 * D;
        const float* r1 = feat + (size_t)s1 * D;
        const float* r2 = feat + (size_t)s2 * D;
        const float* r3 = feat + (size_t)s3 * D;
#pragma unroll
        for (int j = 0; j < R; j++) {
            acc[j] += r0[lane + j * 64];
            acc[j] += r1[lane + j * 64];
            acc[j] += r2[lane + j * 64];
            acc[j] += r3[lane + j * 64];
        }
    }
    for (; i < end; i++) {
        const float* r = feat + (size_t)csr[i] * D;
#pragma unroll
        for (int j = 0; j < R; j++) acc[j] += r[lane + j * 64];
    }
    float inv = inv_deg[node];
#pragma unroll
    for (int j = 0; j < R; j++)
        mean_out[(size_t)node * D + lane + j * 64] = acc[j] * inv;
}

// -------------------- fused dual-A GEMM: C = act(A1@B1 + A2@B2 + bias) ------
// A1,A2: M x K row-major.  B1,B2: K x N row-major.  Tile 128x128, micro 8x8.

#define BM 128
#define BN 128
#define BK 16

__global__ __launch_bounds__(256) void gemm_dual(
    const float* __restrict__ A1, const float* __restrict__ A2,
    const float* __restrict__ B1, const float* __restrict__ B2,
    const float* __restrict__ bias, float* __restrict__ C,
    int M, int K, int N, int do_relu) {
    __shared__ float As[BK][BM + 4];  // transposed: As[k][m]
    __shared__ float Bs[BK][BN + 4];
    int t = threadIdx.x;
    int tx = t & 15;        // col group (8 cols)
    int ty = t >> 4;        // row group (8 rows)
    int row0 = blockIdx.x * BM;
    int col0 = blockIdx.y * BN;

    float acc[8][8];
#pragma unroll
    for (int i = 0; i < 8; i++)
#pragma unroll
        for (int j = 0; j < 8; j++) acc[i][j] = 0.f;

    for (int mat = 0; mat < 2; mat++) {
        const float* A = mat ? A2 : A1;
        const float* B = mat ? B2 : B1;
        for (int k0 = 0; k0 < K; k0 += BK) {
            // A tile: BM rows x BK k, store transposed As[k][m]
#pragma unroll
            for (int pass = 0; pass < 2; pass++) {
                int r = pass * 64 + (t >> 2);  // 0..127
                int kk = (t & 3) * 4;          // 0,4,8,12
                int grow = row0 + r;
                float4 v = make_float4(0.f, 0.f, 0.f, 0.f);
                if (grow < M)
                    v = *(const float4*)(A + (size_t)grow * K + k0 + kk);
                As[kk + 0][r] = v.x;
                As[kk + 1][r] = v.y;
                As[kk + 2][r] = v.z;
                As[kk + 3][r] = v.w;
            }
            // B tile: BK rows x BN cols
#pragma unroll
            for (int pass = 0; pass < 2; pass++) {
                int r = pass * 8 + (t >> 5);   // 0..15
                int c = (t & 31) * 4;          // 0..124
                float4 v = *(const float4*)(B + (size_t)(k0 + r) * N + col0 + c);
                *(float4*)&Bs[r][c] = v;
            }
            __syncthreads();
#pragma unroll
            for (int kk = 0; kk < BK; kk++) {
                float4 a0 = *(const float4*)&As[kk][ty * 8];
                float4 a1 = *(const float4*)&As[kk][ty * 8 + 4];
                float4 b0 = *(const float4*)&Bs[kk][tx * 8];
                float4 b1 = *(const float4*)&Bs[kk][tx * 8 + 4];
                float a[8] = {a0.x, a0.y, a0.z, a0.w, a1.x, a1.y, a1.z, a1.w};
                float b[8] = {b0.x, b0.y, b0.z, b0.w, b1.x, b1.y, b1.z, b1.w};
#pragma unroll
                for (int i = 0; i < 8; i++)
#pragma unroll
                    for (int j = 0; j < 8; j++) acc[i][j] += a[i] * b[j];
            }
            __syncthreads();
        }
    }

    // epilogue: bias (+ relu), float4 stores
#pragma unroll
    for (int i = 0; i < 8; i++) {
        int grow = row0 + ty * 8 + i;
        if (grow >= M) continue;
#pragma unroll
        for (int j = 0; j < 8; j += 4) {
            int gcol = col0 + tx * 8 + j;
            float4 v;
            v.x = acc[i][j + 0] + bias[gcol + 0];
            v.y = acc[i][j + 1] + bias[gcol + 1];
            v.z = acc[i][j + 2] + bias[gcol + 2];
            v.w = acc[i][j + 3] + bias[gcol + 3];
            if (do_relu) {
                v.x = fmaxf(v.x, 0.f);
                v.y = fmaxf(v.y, 0.f);
                v.z = fmaxf(v.z, 0.f);
                v.w = fmaxf(v.w, 0.f);
            }
            *(float4*)(C + (size_t)grow * N + gcol) = v;
        }
    }
}

// -------------------- launcher --------------------

extern "C" void kernel_launch(void* const* d_in, const int* in_sizes, int n_in,
                              void* d_out, int out_size, void* d_ws, size_t ws_size,
                              hipStream_t stream) {
    const float* x   = (const float*)d_in[0];
    const int*  eidx = (const int*)d_in[1];
    const float* Wl1 = (const float*)d_in[2];
    const float* bl1 = (const float*)d_in[3];
    const float* Wr1 = (const float*)d_in[4];
    const float* Wl2 = (const float*)d_in[5];
    const float* bl2 = (const float*)d_in[6];
    const float* Wr2 = (const float*)d_in[7];

    int n_nodes = in_sizes[0] / IN_DIM;
    int n_edges = in_sizes[1] / 2;
    const int* src = eidx;
    const int* dst = eidx + n_edges;

    // workspace carve (256B aligned)
    char* p = (char*)d_ws;
    auto alloc = [&](size_t bytes) {
        void* q = (void*)p;
        p += (bytes + 255) & ~(size_t)255;
        return q;
    };
    int*   deg     = (int*)alloc((size_t)n_nodes * 4);
    int*   offs    = (int*)alloc((size_t)(n_nodes + 1) * 4);
    int*   cursor  = (int*)alloc((size_t)n_nodes * 4);
    float* inv_deg = (float*)alloc((size_t)n_nodes * 4);
    int*   bsums   = (int*)alloc(256 * 4);
    int*   csr     = (int*)alloc((size_t)n_edges * 4);
    // meanbuf reused: mean1 (n*128) then mean2 (n*256)
    float* meanbuf = (float*)alloc((size_t)n_nodes * HID_DIM * 4);
    float* h       = (float*)alloc((size_t)n_nodes * HID_DIM * 4);

    int eb = (n_edges + 255) / 256;
    int nb = (n_nodes + 255) / 256;

    hipMemsetAsync(deg, 0, (size_t)n_nodes * 4, stream);
    hist_kernel<<<eb, 256, 0, stream>>>(dst, n_edges, deg);
    block_sum_kernel<<<nb, 256, 0, stream>>>(deg, n_nodes, bsums);
    scan_bsums_kernel<<<1, 256, 0, stream>>>(bsums, nb);
    finalize_kernel<<<nb, 256, 0, stream>>>(deg, bsums, n_nodes, n_edges,
                                            offs, cursor, inv_deg);
    scatter_kernel<<<eb, 256, 0, stream>>>(src, dst, n_edges, cursor, csr);

    // layer 1
    agg_kernel<IN_DIM><<<(n_nodes + 3) / 4, 256, 0, stream>>>(
        x, offs, csr, inv_deg, n_nodes, meanbuf);
    dim3 g1((n_nodes + BM - 1) / BM, HID_DIM / BN);
    gemm_dual<<<g1, 256, 0, stream>>>(meanbuf, x, Wl1, Wr1, bl1, h,
                                      n_nodes, IN_DIM, HID_DIM, 1);

    // layer 2
    agg_kernel<HID_DIM><<<(n_nodes + 3) / 4, 256, 0, stream>>>(
        h, offs, csr, inv_deg, n_nodes, meanbuf);
    dim3 g2((n_nodes + BM - 1) / BM, OUT_DIM / BN);
    gemm_dual<<<g2, 256, 0, stream>>>(meanbuf, h, Wl2, Wr2, bl2, (float*)d_out,
                                      n_nodes, HID_DIM, OUT_DIM, 0);
}

// Round 2
// 496.611 us; speedup vs baseline: 1.6275x; 1.6275x over previous
//
#include <hip/hip_runtime.h>

// ---------------------------------------------------------------------------
// GraphSAGE 2-layer, bf16 restructure:
//   CSR build (rebuilt every call; ws is re-poisoned)
//   xb = bf16(x); WT* = bf16(W^T) (pre-transposed weights for MFMA B-frags)
//   agg(xb) -> mean1b (bf16)
//   MFMA gemm: hb = bf16(relu(mean1b@Wl1 + xb@Wr1 + bl1))
//   MFMA gemm: pb = bf16(hb@Wl2)            [projection-first: mean commutes]
//   agg(pb) -> mean2 (fp32)
//   MFMA gemm: out = hb@Wr2 + bl2 + mean2   (fp32 out)
// ---------------------------------------------------------------------------

#define IN_DIM 128
#define HID_DIM 256
#define OUT_DIM 128

typedef unsigned short u16;
typedef unsigned int u32;
typedef __attribute__((ext_vector_type(8))) short short8;   // 8 bf16 (4 VGPRs)
typedef __attribute__((ext_vector_type(4))) float float4v;  // 4 fp32 acc

static __device__ __forceinline__ u16 f2bf(float f) {
    u32 u = __builtin_bit_cast(u32, f);
    u = (u + 0x7fffu + ((u >> 16) & 1u)) >> 16;
    return (u16)u;
}
static __device__ __forceinline__ float bf2f(u32 lo16) {
    return __builtin_bit_cast(float, lo16 << 16);
}

// -------------------- CSR build --------------------

__global__ void hist_kernel(const int* __restrict__ dst, int n_edges,
                            int* __restrict__ deg) {
    int i = blockIdx.x * blockDim.x + threadIdx.x;
    if (i < n_edges) atomicAdd(&deg[dst[i]], 1);
}

__global__ void block_sum_kernel(const int* __restrict__ deg, int n,
                                 int* __restrict__ bsums) {
    __shared__ int s[256];
    int i = blockIdx.x * 256 + threadIdx.x;
    s[threadIdx.x] = (i < n) ? deg[i] : 0;
    __syncthreads();
    for (int off = 128; off > 0; off >>= 1) {
        if (threadIdx.x < off) s[threadIdx.x] += s[threadIdx.x + off];
        __syncthreads();
    }
    if (threadIdx.x == 0) bsums[blockIdx.x] = s[0];
}

__global__ void scan_bsums_kernel(int* __restrict__ bsums, int nblk) {
    __shared__ int s[256];
    int t = threadIdx.x;
    int v = (t < nblk) ? bsums[t] : 0;
    s[t] = v;
    __syncthreads();
    for (int off = 1; off < 256; off <<= 1) {
        int add = (t >= off) ? s[t - off] : 0;
        __syncthreads();
        s[t] += add;
        __syncthreads();
    }
    if (t < nblk) bsums[t] = s[t] - v;
}

__global__ void finalize_kernel(const int* __restrict__ deg,
                                const int* __restrict__ bsums,
                                int n, int n_edges,
                                int* __restrict__ offs, int* __restrict__ cursor,
                                float* __restrict__ inv_deg) {
    __shared__ int s[256];
    int t = threadIdx.x;
    int i = blockIdx.x * 256 + t;
    int v = (i < n) ? deg[i] : 0;
    s[t] = v;
    __syncthreads();
    for (int off = 1; off < 256; off <<= 1) {
        int add = (t >= off) ? s[t - off] : 0;
        __syncthreads();
        s[t] += add;
        __syncthreads();
    }
    if (i < n) {
        int excl = bsums[blockIdx.x] + s[t] - v;
        offs[i] = excl;
        cursor[i] = excl;
        inv_deg[i] = 1.0f / (float)(v > 0 ? v : 1);
    }
    if (i == 0) offs[n] = n_edges;
}

__global__ void scatter_kernel(const int* __restrict__ src,
                               const int* __restrict__ dst, int n_edges,
                               int* __restrict__ cursor, int* __restrict__ csr) {
    int i = blockIdx.x * blockDim.x + threadIdx.x;
    if (i < n_edges) {
        int p = atomicAdd(&cursor[dst[i]], 1);
        csr[p] = src[i];
    }
}

// -------------------- casts --------------------

__global__ void cast_x_kernel(const float* __restrict__ in,
                              u16* __restrict__ out, int n4) {
    int i = blockIdx.x * 256 + threadIdx.x;
    if (i < n4) {
        float4 v = *(const float4*)(in + (size_t)i * 4);
        u32 lo = (u32)f2bf(v.x) | ((u32)f2bf(v.y) << 16);
        u32 hi = (u32)f2bf(v.z) | ((u32)f2bf(v.w) << 16);
        uint2 o;
        o.x = lo;
        o.y = hi;
        *(uint2*)(out + (size_t)i * 4) = o;
    }
}

// in: [R][C] fp32 row-major -> out: [C][R] bf16 row-major
__global__ void transpose_cast_kernel(const float* __restrict__ in,
                                      u16* __restrict__ out, int R, int C) {
    int i = blockIdx.x * 256 + threadIdx.x;
    if (i < R * C) {
        int c = i / R;
        int r = i - c * R;
        out[i] = f2bf(in[(size_t)r * C + c]);
    }
}

// -------------------- mean aggregation (D=128 bf16, 1 wave/node) -----------

__global__ __launch_bounds__(256) void agg_bf16(
    const u16* __restrict__ feat, const int* __restrict__ offs,
    const int* __restrict__ csr, const float* __restrict__ inv_deg,
    int n_nodes, u16* __restrict__ out_bf, float* __restrict__ out_f) {
    int wave = threadIdx.x >> 6;
    int lane = threadIdx.x & 63;
    int node = blockIdx.x * 4 + wave;
    if (node >= n_nodes) return;
    int beg = offs[node], end = offs[node + 1];
    float a0 = 0.f, a1 = 0.f;
    int i = beg;
    for (; i + 8 <= end; i += 8) {
        u32 v[8];
#pragma unroll
        for (int j = 0; j < 8; j++) {
            int s = csr[i + j];
            v[j] = *(const u32*)(feat + (size_t)s * 128 + lane * 2);
        }
#pragma unroll
        for (int j = 0; j < 8; j++) {
            a0 += bf2f(v[j] & 0xffffu);
            a1 += bf2f(v[j] >> 16);
        }
    }
    for (; i < end; i++) {
        int s = csr[i];
        u32 v = *(const u32*)(feat + (size_t)s * 128 + lane * 2);
        a0 += bf2f(v & 0xffffu);
        a1 += bf2f(v >> 16);
    }
    float inv = inv_deg[node];
    a0 *= inv;
    a1 *= inv;
    if (out_bf) {
        u32 pv = (u32)f2bf(a0) | ((u32)f2bf(a1) << 16);
        *(u32*)(out_bf + (size_t)node * 128 + lane * 2) = pv;
    } else {
        float2 o;
        o.x = a0;
        o.y = a1;
        *(float2*)(out_f + (size_t)node * 128 + lane * 2) = o;
    }
}

// -------------------- MFMA GEMM --------------------
// C[M,N] = act( sum_mat A_mat[M,K] @ B_mat[K,N] + bias + addend )
// A bf16 row-major; BT bf16 = B^T, [N][K] row-major (so B-frags are
// contiguous 16B reads). Block: 256 thr = 4 waves; tile 128(M) x 64(N);
// wave = 32(M) x 64(N) via 2x4 grid of 16x16x32 mfma.
// Frag layouts (verified m89/m91/m120): A[m=lane&15][k=quad*8+j],
// B[k=quad*8+j][n=lane&15], C/D: col=lane&15, row=quad*4+reg.

__global__ __launch_bounds__(256) void gemm_bf16(
    const u16* __restrict__ A1, const u16* __restrict__ A2,
    const u16* __restrict__ BT1, const u16* __restrict__ BT2,
    const float* __restrict__ bias, const float* __restrict__ addend,
    u16* __restrict__ out_bf, float* __restrict__ out_f,
    int M, int K, int N, int nmat, int relu) {
    extern __shared__ u16 Bs[];
    const int KP = K + 8;  // +8 bf16 pad: frag reads land 2-way (free)
    int t = threadIdx.x;
    int colbase = blockIdx.y * 64;

    // stage B^T panels: nmat * 64 rows * K bf16, vectorized 16B
    int total8 = nmat * 64 * K / 8;
    for (int c = t; c < total8; c += 256) {
        int flat = c * 8;
        int mat = flat / (64 * K);
        int rem = flat - mat * 64 * K;
        int n = rem / K;
        int k = rem - n * K;
        const u16* srcp = (mat ? BT2 : BT1) + (size_t)(colbase + n) * K + k;
        *(uint4*)(&Bs[mat * 64 * KP + n * KP + k]) = *(const uint4*)srcp;
    }
    __syncthreads();

    int lane = t & 63;
    int wave = t >> 6;
    int quad = lane >> 4;
    int l16 = lane & 15;
    int row_base = blockIdx.x * 128 + wave * 32;

    float4v zero = {0.f, 0.f, 0.f, 0.f};
    float4v acc[2][4];
#pragma unroll
    for (int mi = 0; mi < 2; mi++)
#pragma unroll
        for (int ni = 0; ni < 4; ni++) acc[mi][ni] = zero;

    for (int mat = 0; mat < nmat; mat++) {
        const u16* A = mat ? A2 : A1;
        const u16* Bp = &Bs[mat * 64 * KP];
        for (int ks = 0; ks < (K >> 5); ks++) {
            int k = ks * 32 + quad * 8;
            short8 af[2] = {{0, 0, 0, 0, 0, 0, 0, 0}, {0, 0, 0, 0, 0, 0, 0, 0}};
#pragma unroll
            for (int mi = 0; mi < 2; mi++) {
                int m = row_base + mi * 16 + l16;
                if (m < M) af[mi] = *(const short8*)(A + (size_t)m * K + k);
            }
#pragma unroll
            for (int ni = 0; ni < 4; ni++) {
                short8 bfr = *(const short8*)(Bp + (ni * 16 + l16) * KP + k);
                acc[0][ni] = __builtin_amdgcn_mfma_f32_16x16x32_bf16(
                    af[0], bfr, acc[0][ni], 0, 0, 0);
                acc[1][ni] = __builtin_amdgcn_mfma_f32_16x16x32_bf16(
                    af[1], bfr, acc[1][ni], 0, 0, 0);
            }
        }
    }

    // epilogue
#pragma unroll
    for (int mi = 0; mi < 2; mi++) {
#pragma unroll
        for (int r = 0; r < 4; r++) {
            int row = row_base + mi * 16 + quad * 4 + r;
            if (row >= M) continue;
#pragma unroll
            for (int ni = 0; ni < 4; ni++) {
                int col = colbase + ni * 16 + l16;
                float v = acc[mi][ni][r];
                if (bias) v += bias[col];
                if (addend) v += addend[(size_t)row * N + col];
                if (relu) v = fmaxf(v, 0.f);
                if (out_bf)
                    out_bf[(size_t)row * N + col] = f2bf(v);
                else
                    out_f[(size_t)row * N + col] = v;
            }
        }
    }
}

// -------------------- launcher --------------------

extern "C" void kernel_launch(void* const* d_in, const int* in_sizes, int n_in,
                              void* d_out, int out_size, void* d_ws, size_t ws_size,
                              hipStream_t stream) {
    const float* x   = (const float*)d_in[0];
    const int*  eidx = (const int*)d_in[1];
    const float* Wl1 = (const float*)d_in[2];
    const float* bl1 = (const float*)d_in[3];
    const float* Wr1 = (const float*)d_in[4];
    const float* Wl2 = (const float*)d_in[5];
    const float* bl2 = (const float*)d_in[6];
    const float* Wr2 = (const float*)d_in[7];

    int n_nodes = in_sizes[0] / IN_DIM;
    int n_edges = in_sizes[1] / 2;
    const int* src = eidx;
    const int* dst = eidx + n_edges;

    char* p = (char*)d_ws;
    auto alloc = [&](size_t bytes) {
        void* q = (void*)p;
        p += (bytes + 255) & ~(size_t)255;
        return q;
    };
    int*   deg     = (int*)alloc((size_t)n_nodes * 4);
    int*   offs    = (int*)alloc((size_t)(n_nodes + 1) * 4);
    int*   cursor  = (int*)alloc((size_t)n_nodes * 4);
    float* inv_deg = (float*)alloc((size_t)n_nodes * 4);
    int*   bsums   = (int*)alloc(256 * 4);
    int*   csr     = (int*)alloc((size_t)n_edges * 4);
    u16*   xb      = (u16*)alloc((size_t)n_nodes * IN_DIM * 2);
    u16*   mean1b  = (u16*)alloc((size_t)n_nodes * IN_DIM * 2);
    u16*   hb      = (u16*)alloc((size_t)n_nodes * HID_DIM * 2);
    u16*   pb      = (u16*)alloc((size_t)n_nodes * OUT_DIM * 2);
    float* mean2   = (float*)alloc((size_t)n_nodes * OUT_DIM * 4);
    u16*   WTl1b   = (u16*)alloc((size_t)IN_DIM * HID_DIM * 2);
    u16*   WTr1b   = (u16*)alloc((size_t)IN_DIM * HID_DIM * 2);
    u16*   WTl2b   = (u16*)alloc((size_t)HID_DIM * OUT_DIM * 2);
    u16*   WTr2b   = (u16*)alloc((size_t)HID_DIM * OUT_DIM * 2);

    int eb = (n_edges + 255) / 256;
    int nb = (n_nodes + 255) / 256;

    // CSR build
    hipMemsetAsync(deg, 0, (size_t)n_nodes * 4, stream);
    hist_kernel<<<eb, 256, 0, stream>>>(dst, n_edges, deg);
    block_sum_kernel<<<nb, 256, 0, stream>>>(deg, n_nodes, bsums);
    scan_bsums_kernel<<<1, 256, 0, stream>>>(bsums, nb);
    finalize_kernel<<<nb, 256, 0, stream>>>(deg, bsums, n_nodes, n_edges,
                                            offs, cursor, inv_deg);
    scatter_kernel<<<eb, 256, 0, stream>>>(src, dst, n_edges, cursor, csr);

    // casts
    int n4 = n_nodes * IN_DIM / 4;
    cast_x_kernel<<<(n4 + 255) / 256, 256, 0, stream>>>(x, xb, n4);
    int wsz = IN_DIM * HID_DIM;  // 32768, same for all 4
    transpose_cast_kernel<<<(wsz + 255) / 256, 256, 0, stream>>>(Wl1, WTl1b, IN_DIM, HID_DIM);
    transpose_cast_kernel<<<(wsz + 255) / 256, 256, 0, stream>>>(Wr1, WTr1b, IN_DIM, HID_DIM);
    transpose_cast_kernel<<<(wsz + 255) / 256, 256, 0, stream>>>(Wl2, WTl2b, HID_DIM, OUT_DIM);
    transpose_cast_kernel<<<(wsz + 255) / 256, 256, 0, stream>>>(Wr2, WTr2b, HID_DIM, OUT_DIM);

    int gx = (n_nodes + 127) / 128;

    // layer 1: agg x, h = relu(mean1@Wl1 + x@Wr1 + bl1)
    agg_bf16<<<(n_nodes + 3) / 4, 256, 0, stream>>>(xb, offs, csr, inv_deg,
                                                    n_nodes, mean1b, nullptr);
    {
        dim3 g(gx, HID_DIM / 64);
        size_t smem = 2 * 64 * (size_t)(IN_DIM + 8) * 2;
        gemm_bf16<<<g, 256, smem, stream>>>(mean1b, xb, WTl1b, WTr1b, bl1,
                                            nullptr, hb, nullptr,
                                            n_nodes, IN_DIM, HID_DIM, 2, 1);
    }

    // layer 2 projection-first: pb = hb@Wl2
    {
        dim3 g(gx, OUT_DIM / 64);
        size_t smem = 1 * 64 * (size_t)(HID_DIM + 8) * 2;
        gemm_bf16<<<g, 256, smem, stream>>>(hb, nullptr, WTl2b, nullptr,
                                            nullptr, nullptr, pb, nullptr,
                                            n_nodes, HID_DIM, OUT_DIM, 1, 0);
    }
    // mean2 = mean(pb)  (fp32 out)
    agg_bf16<<<(n_nodes + 3) / 4, 256, 0, stream>>>(pb, offs, csr, inv_deg,
                                                    n_nodes, nullptr, mean2);
    // out = hb@Wr2 + bl2 + mean2
    {
        dim3 g(gx, OUT_DIM / 64);
        size_t smem = 1 * 64 * (size_t)(HID_DIM + 8) * 2;
        gemm_bf16<<<g, 256, smem, stream>>>(hb, nullptr, WTr2b, nullptr,
                                            bl2, mean2, nullptr, (float*)d_out,
                                            n_nodes, HID_DIM, OUT_DIM, 1, 0);
    }
}